// Round 4
// baseline (14482.788 us; speedup 1.0000x reference)
//
#include <hip/hip_runtime.h>

// B=64, T=512, D=96, H=256
constexpr int Bb = 64;
constexpr int Tt = 512;
constexpr int Dd = 96;
constexpr int Hh = 256;
constexpr int BH = Bb * Hh;   // 16384 elements per h buffer

__device__ __forceinline__ float sigf(float v) { return 1.0f / (1.0f + __expf(-v)); }

__device__ __forceinline__ unsigned long long aload64(const unsigned long long* p) {
    return __hip_atomic_load(p, __ATOMIC_RELAXED, __HIP_MEMORY_SCOPE_AGENT);
}
__device__ __forceinline__ void astore64(unsigned long long* p, unsigned long long v) {
    __hip_atomic_store(p, v, __ATOMIC_RELAXED, __HIP_MEMORY_SCOPE_AGENT);
}

template<int G>
__device__ __forceinline__ void load8(float* wv, const float* __restrict__ M,
                                      int ld, int kb) {
    #pragma unroll
    for (int u = 0; u < 8; ++u)
        #pragma unroll
        for (int g = 0; g < G; ++g)
            wv[u * G + g] = M[(long)(kb + u) * ld + g * Hh];
}

template<int G>
__device__ __forceinline__ void fma8(const float* wv, const float* __restrict__ sA,
                                     int kb, float4* acc) {
    #pragma unroll
    for (int u = 0; u < 8; ++u) {
        const float4 a4 = *(const float4*)(sA + (size_t)(kb + u) * 4);
        #pragma unroll
        for (int g = 0; g < G; ++g) {
            const float w = wv[u * G + g];
            acc[g].x = fmaf(w, a4.x, acc[g].x);
            acc[g].y = fmaf(w, a4.y, acc[g].y);
            acc[g].z = fmaf(w, a4.z, acc[g].z);
            acc[g].w = fmaf(w, a4.w, acc[g].w);
        }
    }
}

template<int G>
__device__ __forceinline__ void gemm_range(const float* __restrict__ M, int ld,
                                           const float* __restrict__ sA,
                                           int k0, int k1, float4* acc) {
    const int n8 = (k1 - k0) >> 3;
    float wv0[8 * G], wv1[8 * G];
    if (n8 > 0) {
        load8<G>(wv0, M, ld, k0);
        int c = 0;
        for (; c + 2 <= n8; c += 2) {
            load8<G>(wv1, M, ld, k0 + (c + 1) * 8);
            fma8<G>(wv0, sA, k0 + c * 8, acc);
            if (c + 2 < n8) load8<G>(wv0, M, ld, k0 + (c + 2) * 8);
            fma8<G>(wv1, sA, k0 + (c + 1) * 8, acc);
        }
        if (c < n8) fma8<G>(wv0, sA, k0 + c * 8, acc);
    }
    for (int k = k0 + (n8 << 3); k < k1; ++k) {
        const float4 a4 = *(const float4*)(sA + (size_t)k * 4);
        #pragma unroll
        for (int g = 0; g < G; ++g) {
            const float w = M[(long)k * ld + g * Hh];
            acc[g].x = fmaf(w, a4.x, acc[g].x);
            acc[g].y = fmaf(w, a4.y, acc[g].y);
            acc[g].z = fmaf(w, a4.z, acc[g].z);
            acc[g].w = fmaf(w, a4.w, acc[g].w);
        }
    }
}

__device__ __forceinline__ void addslot(float* sG, int slot, int lane, const float4& a) {
    atomicAdd(&sG[slot * 256 +   0 + lane], a.x);
    atomicAdd(&sG[slot * 256 +  64 + lane], a.y);
    atomicAdd(&sG[slot * 256 + 128 + lane], a.z);
    atomicAdd(&sG[slot * 256 + 192 + lane], a.w);
}

// stage 1024 tagged elements (4 rows x 256 cols), 2 per thread, single poll loop
__device__ __forceinline__ void stage2(const unsigned long long* __restrict__ buf,
                                       int rowbase, unsigned want,
                                       float* __restrict__ sA, int koff, int tid) {
    const int i0 = tid, i1 = tid + 512;
    const int r0 = i0 & 3, k0 = i0 >> 2, r1 = i1 & 3, k1 = i1 >> 2;
    const unsigned long long* p0 = buf + (rowbase + r0) * Hh + k0;
    const unsigned long long* p1 = buf + (rowbase + r1) * Hh + k1;
    unsigned long long v0 = 0, v1 = 0;
    bool d0 = false, d1 = false;
    do {
        if (!d0) { v0 = aload64(p0); d0 = ((unsigned)v0 == want); }
        if (!d1) { v1 = aload64(p1); d1 = ((unsigned)v1 == want); }
    } while (!(d0 && d1));
    sA[(koff + k0) * 4 + r0] = __uint_as_float((unsigned)(v0 >> 32));
    sA[(koff + k1) * 4 + r1] = __uint_as_float((unsigned)(v1 >> 32));
}

// stage 2048 tagged elements from two buffers (layer-1: lower h(t) + own h(t-1))
__device__ __forceinline__ void stage4(const unsigned long long* __restrict__ blow,
                                       unsigned wlow,
                                       const unsigned long long* __restrict__ bown,
                                       unsigned wown, int rowbase,
                                       float* __restrict__ sA, int tid) {
    const unsigned long long* p[4];
    unsigned want[4];
    int sidx[4];
    #pragma unroll
    for (int e = 0; e < 4; ++e) {
        const int i = tid + e * 512;          // 0..2047
        const bool low = (i < 1024);
        const int ii = low ? i : i - 1024;
        const int r = ii & 3, k = ii >> 2;
        p[e]    = (low ? blow : bown) + (rowbase + r) * Hh + k;
        want[e] = low ? wlow : wown;
        sidx[e] = ((low ? 0 : 256) + k) * 4 + r;
    }
    unsigned long long v[4] = {0, 0, 0, 0};
    bool d[4] = {false, false, false, false};
    for (;;) {
        bool all = true;
        #pragma unroll
        for (int e = 0; e < 4; ++e) {
            if (!d[e]) { v[e] = aload64(p[e]); d[e] = ((unsigned)v[e] == want[e]); }
            all &= d[e];
        }
        if (all) break;
    }
    #pragma unroll
    for (int e = 0; e < 4; ++e)
        sA[sidx[e]] = __uint_as_float((unsigned)(v[e] >> 32));
}

// ws layout:
//  bytes [0, 1MB):  8 tagged h buffers [chain][layer][slot] x BH u64
//                   u64 = (float_bits << 32) | tag; tag for h(t) is t+1;
//                   memset(0) encodes h(-1)=0 with tag 0.
//  bytes [1MB, 1MB+32KB): flags, one int per block, 128B spacing.
extern "C" __global__ void __launch_bounds__(512, 2)
rnn_persist(const float* __restrict__ x, const int* __restrict__ lengths,
            const float* __restrict__ gW0, const float* __restrict__ gU0,
            const float* __restrict__ gbi0, const float* __restrict__ gbr0,
            const float* __restrict__ gW1, const float* __restrict__ gU1,
            const float* __restrict__ gbi1, const float* __restrict__ gbr1,
            const float* __restrict__ lW0, const float* __restrict__ lU0,
            const float* __restrict__ lb0,
            const float* __restrict__ lW1, const float* __restrict__ lU1,
            const float* __restrict__ lb1,
            const float* __restrict__ outW, const float* __restrict__ outb,
            float* __restrict__ out, float* __restrict__ ws)
{
    const int tid  = threadIdx.x;
    const int lane = tid & 63;
    const int wave = tid >> 6;

    // blockIdx = rg*16 + slice; XCD = blockIdx%8 = slice%8 -> weight slice L2-resident
    const int slice = blockIdx.x & 15;
    const int rg    = blockIdx.x >> 4;        // 16 rowgroups x 4 rows
    const int chain = slice >> 3;
    const int layer = (slice >> 2) & 1;
    const int jt    = slice & 3;
    const int rowbase = rg * 4;
    const int cpos  = jt * 64 + lane;

    unsigned long long* H = (unsigned long long*)ws;
    unsigned long long* own   = H + (size_t)((chain * 2 + layer) * 2) * BH;
    unsigned long long* lower = H + (size_t)((chain * 2 + 0) * 2) * BH;
    int* flags  = (int*)((char*)ws + (1 << 20));
    int* myflag = flags + (((chain * 2 + layer) * 16 + rg) * 4 + jt) * 32;

    const int Ka = layer ? Hh : Dd;
    const int KA = Ka + Hh;                   // 352 or 512
    const int ld = chain ? 4 * Hh : 3 * Hh;

    const float* Wm; const float* Um;
    if (chain == 0) { Wm = layer ? gW1 : gW0; Um = layer ? gU1 : gU0; }
    else            { Wm = layer ? lW1 : lW0; Um = layer ? lU1 : lU0; }
    const float* Wp = Wm + cpos;
    const float* Up = Um + cpos - (long)Ka * ld;

    __shared__ __align__(16) float sA[512 * 4];   // A^T[k][4 rows]
    __shared__ float sG[4 * 256];

    const int r = tid >> 6, cc = tid & 63, col = jt * 64 + cc;
    int grow = 0, mylen = 0;
    float b0 = 0, b1 = 0, b2 = 0, b3 = 0, ow = 0, creg = 0.0f;
    if (tid < 256) {
        grow = rowbase + r;
        mylen = lengths[grow];
        if (chain == 0) {
            const float* bi = layer ? gbi1 : gbi0;
            const float* br = layer ? gbr1 : gbr0;
            b0 = bi[col] + br[col];
            b1 = bi[Hh + col] + br[Hh + col];
            b2 = bi[2 * Hh + col];
            b3 = br[2 * Hh + col];
        } else {
            const float* bb = layer ? lb1 : lb0;
            b0 = bb[col]; b1 = bb[Hh + col]; b2 = bb[2 * Hh + col]; b3 = bb[3 * Hh + col];
        }
        if (layer == 1) ow = outW[chain * Hh + col];
    }
    const float outb0 = outb[0];
    const int kpw = KA >> 3;

    for (int rd = 0; rd <= Tt; ++rd) {
        const bool active = (layer == 0) ? (rd < Tt) : (rd >= 1);
        const int t = (layer == 0) ? rd : rd - 1;

        if (active) {
            // ---- stage A^T: the tagged poll IS the sync (one IF$ hop) ----
            if (layer == 0) {
                if (tid < 4 * Dd) {
                    const int rr2 = tid & 3, k = tid >> 2;
                    sA[k * 4 + rr2] = x[((long)(rowbase + rr2) * Tt + t) * Dd + k];
                }
                // own h(t-1): slot (t-1)&1, tag t
                stage2(own + (size_t)((t - 1) & 1) * BH, rowbase, (unsigned)t,
                       sA, Dd, tid);
            } else {
                // lower h(t): slot t&1, tag t+1; own h(t-1): slot (t-1)&1, tag t
                stage4(lower + (size_t)(t & 1) * BH, (unsigned)(t + 1),
                       own + (size_t)((t - 1) & 1) * BH, (unsigned)t,
                       rowbase, sA, tid);
            }
            for (int i = tid; i < 4 * 256; i += 512) sG[i] = 0.0f;
            __syncthreads();

            // ---- GEMM (unchanged from R3) ----
            {
                const int k0 = wave * kpw, k1 = k0 + kpw;
                if (chain == 0) {
                    float4 acc[3];
                    int a = k0, b = (k1 < Ka) ? k1 : Ka;
                    if (a < b) {
                        acc[0] = acc[1] = acc[2] = float4{0, 0, 0, 0};
                        gemm_range<3>(Wp, ld, sA, a, b, acc);
                        addslot(sG, 0, lane, acc[0]);
                        addslot(sG, 1, lane, acc[1]);
                        addslot(sG, 2, lane, acc[2]);
                    }
                    a = (k0 > Ka) ? k0 : Ka; b = k1;
                    if (a < b) {
                        acc[0] = acc[1] = acc[2] = float4{0, 0, 0, 0};
                        gemm_range<3>(Up, ld, sA, a, b, acc);
                        addslot(sG, 0, lane, acc[0]);
                        addslot(sG, 1, lane, acc[1]);
                        addslot(sG, 3, lane, acc[2]);
                    }
                } else {
                    float4 acc[4];
                    int a = k0, b = (k1 < Ka) ? k1 : Ka;
                    if (a < b) {
                        acc[0] = acc[1] = acc[2] = acc[3] = float4{0, 0, 0, 0};
                        gemm_range<4>(Wp, ld, sA, a, b, acc);
                        addslot(sG, 0, lane, acc[0]); addslot(sG, 1, lane, acc[1]);
                        addslot(sG, 2, lane, acc[2]); addslot(sG, 3, lane, acc[3]);
                    }
                    a = (k0 > Ka) ? k0 : Ka; b = k1;
                    if (a < b) {
                        acc[0] = acc[1] = acc[2] = acc[3] = float4{0, 0, 0, 0};
                        gemm_range<4>(Up, ld, sA, a, b, acc);
                        addslot(sG, 0, lane, acc[0]); addslot(sG, 1, lane, acc[1]);
                        addslot(sG, 2, lane, acc[2]); addslot(sG, 3, lane, acc[3]);
                    }
                }
            }
            __syncthreads();

            // ---- clobber-safety (L0 only, off critical path, instant in steady state):
            // before overwriting h_l0(t-2) ensure L1 finished round t-1 (it staged h_l0(t-2)).
            if (layer == 0) {
                if (wave == 0) {
                    const int* fp = flags + (((chain * 2 + 1) * 16 + rg) * 4 + (lane & 3)) * 32;
                    bool ok = (lane >= 4);
                    for (;;) {
                        if (!ok) ok = (__hip_atomic_load(fp, __ATOMIC_ACQUIRE,
                                                         __HIP_MEMORY_SCOPE_AGENT) >= rd);
                        if ((__ballot(ok) & 0xFull) == 0xFull) break;
                        __builtin_amdgcn_s_sleep(2);
                    }
                }
                __syncthreads();
            }

            // ---- state update + tagged publish ----
            if (tid < 256) {
                const float s0 = sG[tid], s1 = sG[256 + tid];
                const float s2 = sG[512 + tid], s3 = sG[768 + tid];
                const float hold = sA[(Ka + col) * 4 + r];
                const bool frozen = (t >= mylen);
                float hn;
                if (chain == 0) {
                    const float z   = sigf(s0 + b0);
                    const float rr2 = sigf(s1 + b1);
                    const float hh  = tanhf(s2 + b2 + rr2 * (s3 + b3));
                    hn = z * hold + (1.0f - z) * hh;
                    if (frozen) hn = hold;
                } else {
                    const float i_ = sigf(s0 + b0);
                    const float f_ = sigf(s1 + b1);
                    float cn = f_ * creg + i_ * tanhf(s2 + b2);
                    hn = sigf(s3 + b3) * tanhf(cn);
                    if (frozen) { hn = hold; cn = creg; }
                    creg = cn;
                }
                astore64(&own[(size_t)(t & 1) * BH + grow * Hh + col],
                         ((unsigned long long)__float_as_uint(hn) << 32)
                         | (unsigned)(t + 1));
                if (layer == 1) {
                    float v = hn * ow;
                    for (int o = 32; o > 0; o >>= 1) v += __shfl_down(v, o);
                    if (cc == 0)
                        atomicAdd(&out[(long)grow * Tt + t],
                                  v + ((chain == 1 && jt == 0) ? outb0 : 0.0f));
                }
            }
        }

        // ---- flag publish (clobber-safety bookkeeping only) ----
        __syncthreads();   // drains all waves' stores before the flag
        if (tid == 0) {
            __threadfence();
            __hip_atomic_store(myflag, rd + 1, __ATOMIC_RELEASE, __HIP_MEMORY_SCOPE_AGENT);
        }
    }
}

extern "C" void kernel_launch(void* const* d_in, const int* in_sizes, int n_in,
                              void* d_out, int out_size, void* d_ws, size_t ws_size,
                              hipStream_t stream) {
    const float* x       = (const float*)d_in[0];
    const int*   lengths = (const int*)d_in[1];
    const float* gW0  = (const float*)d_in[2];
    const float* gU0  = (const float*)d_in[3];
    const float* gbi0 = (const float*)d_in[4];
    const float* gbr0 = (const float*)d_in[5];
    const float* gW1  = (const float*)d_in[6];
    const float* gU1  = (const float*)d_in[7];
    const float* gbi1 = (const float*)d_in[8];
    const float* gbr1 = (const float*)d_in[9];
    const float* lW0  = (const float*)d_in[10];
    const float* lU0  = (const float*)d_in[11];
    const float* lb0  = (const float*)d_in[12];
    const float* lW1  = (const float*)d_in[13];
    const float* lU1  = (const float*)d_in[14];
    const float* lb1  = (const float*)d_in[15];
    const float* outW = (const float*)d_in[16];
    const float* outb = (const float*)d_in[17];
    float* out = (float*)d_out;
    float* ws  = (float*)d_ws;

    // zero tagged h buffers (1MB: encodes h(-1)=0, tag 0) + flags (32KB)
    hipMemsetAsync(d_ws, 0, (1 << 20) + 32 * 1024, stream);
    hipMemsetAsync(d_out, 0, (size_t)out_size * sizeof(float), stream);

    rnn_persist<<<dim3(256), dim3(512), 0, stream>>>(
        x, lengths, gW0, gU0, gbi0, gbr0, gW1, gU1, gbi1, gbr1,
        lW0, lU0, lb0, lW1, lU1, lb1, outW, outb, out, ws);
}

// Round 5
// 11161.361 us; speedup vs baseline: 1.2976x; 1.2976x over previous
//
#include <hip/hip_runtime.h>

// B=64, T=512, D=96, H=256
constexpr int Bb = 64;
constexpr int Tt = 512;
constexpr int Dd = 96;
constexpr int Hh = 256;
constexpr int BH = Bb * Hh;   // 16384 elements per h buffer slot

__device__ __forceinline__ float sigf(float v) { return 1.0f / (1.0f + __expf(-v)); }

__device__ __forceinline__ unsigned long long aload64(const unsigned long long* p) {
    return __hip_atomic_load(p, __ATOMIC_RELAXED, __HIP_MEMORY_SCOPE_AGENT);
}

template<int G>
__device__ __forceinline__ void load8(float* wv, const float* __restrict__ M,
                                      int ld, int kb) {
    #pragma unroll
    for (int u = 0; u < 8; ++u)
        #pragma unroll
        for (int g = 0; g < G; ++g)
            wv[u * G + g] = M[(long)(kb + u) * ld + g * Hh];
}

template<int G>
__device__ __forceinline__ void fma8(const float* wv, const float* __restrict__ sA,
                                     int kb, float4* acc) {
    #pragma unroll
    for (int u = 0; u < 8; ++u) {
        const float4 a4 = *(const float4*)(sA + (size_t)(kb + u) * 4);
        #pragma unroll
        for (int g = 0; g < G; ++g) {
            const float w = wv[u * G + g];
            acc[g].x = fmaf(w, a4.x, acc[g].x);
            acc[g].y = fmaf(w, a4.y, acc[g].y);
            acc[g].z = fmaf(w, a4.z, acc[g].z);
            acc[g].w = fmaf(w, a4.w, acc[g].w);
        }
    }
}

template<int G>
__device__ __forceinline__ void gemm_range(const float* __restrict__ M, int ld,
                                           const float* __restrict__ sA,
                                           int k0, int k1, float4* acc) {
    const int n8 = (k1 - k0) >> 3;
    float wv0[8 * G], wv1[8 * G];
    if (n8 > 0) {
        load8<G>(wv0, M, ld, k0);
        int c = 0;
        for (; c + 2 <= n8; c += 2) {
            load8<G>(wv1, M, ld, k0 + (c + 1) * 8);
            fma8<G>(wv0, sA, k0 + c * 8, acc);
            if (c + 2 < n8) load8<G>(wv0, M, ld, k0 + (c + 2) * 8);
            fma8<G>(wv1, sA, k0 + (c + 1) * 8, acc);
        }
        if (c < n8) fma8<G>(wv0, sA, k0 + c * 8, acc);
    }
    for (int k = k0 + (n8 << 3); k < k1; ++k) {
        const float4 a4 = *(const float4*)(sA + (size_t)k * 4);
        #pragma unroll
        for (int g = 0; g < G; ++g) {
            const float w = M[(long)k * ld + g * Hh];
            acc[g].x = fmaf(w, a4.x, acc[g].x);
            acc[g].y = fmaf(w, a4.y, acc[g].y);
            acc[g].z = fmaf(w, a4.z, acc[g].z);
            acc[g].w = fmaf(w, a4.w, acc[g].w);
        }
    }
}

__device__ __forceinline__ void addslot(float* sG, int slot, int lane, const float4& a) {
    atomicAdd(&sG[slot * 256 +   0 + lane], a.x);
    atomicAdd(&sG[slot * 256 +  64 + lane], a.y);
    atomicAdd(&sG[slot * 256 + 128 + lane], a.z);
    atomicAdd(&sG[slot * 256 + 192 + lane], a.w);
}

// stage 1024 tagged elements (4 rows x 256 cols), 2 per thread
__device__ __forceinline__ void stage2(const unsigned long long* __restrict__ buf,
                                       int rowbase, unsigned want,
                                       float* __restrict__ sA, int koff, int tid) {
    const int i0 = tid, i1 = tid + 512;
    const int r0 = i0 & 3, k0 = i0 >> 2, r1 = i1 & 3, k1 = i1 >> 2;
    const unsigned long long* p0 = buf + (rowbase + r0) * Hh + k0;
    const unsigned long long* p1 = buf + (rowbase + r1) * Hh + k1;
    unsigned long long v0 = 0, v1 = 0;
    bool d0 = false, d1 = false;
    do {
        if (!d0) { v0 = aload64(p0); d0 = ((unsigned)v0 == want); }
        if (!d1) { v1 = aload64(p1); d1 = ((unsigned)v1 == want); }
    } while (!(d0 && d1));
    sA[(koff + k0) * 4 + r0] = __uint_as_float((unsigned)(v0 >> 32));
    sA[(koff + k1) * 4 + r1] = __uint_as_float((unsigned)(v1 >> 32));
}

// stage 2048 tagged elements from two buffers (layer-1: lower h(t) + own h(t-1))
__device__ __forceinline__ void stage4(const unsigned long long* __restrict__ blow,
                                       unsigned wlow,
                                       const unsigned long long* __restrict__ bown,
                                       unsigned wown, int rowbase,
                                       float* __restrict__ sA, int tid) {
    const unsigned long long* p[4];
    unsigned want[4];
    int sidx[4];
    #pragma unroll
    for (int e = 0; e < 4; ++e) {
        const int i = tid + e * 512;
        const bool low = (i < 1024);
        const int ii = low ? i : i - 1024;
        const int r = ii & 3, k = ii >> 2;
        p[e]    = (low ? blow : bown) + (rowbase + r) * Hh + k;
        want[e] = low ? wlow : wown;
        sidx[e] = ((low ? 0 : 256) + k) * 4 + r;
    }
    unsigned long long v[4] = {0, 0, 0, 0};
    bool d[4] = {false, false, false, false};
    for (;;) {
        bool all = true;
        #pragma unroll
        for (int e = 0; e < 4; ++e) {
            if (!d[e]) { v[e] = aload64(p[e]); d[e] = ((unsigned)v[e] == want[e]); }
            all &= d[e];
        }
        if (all) break;
    }
    #pragma unroll
    for (int e = 0; e < 4; ++e)
        sA[sidx[e]] = __uint_as_float((unsigned)(v[e] >> 32));
}

// ws layout:
//  bytes [0, 2MB): 4 units [chain][layer], each 4 ring slots x BH u64
//                  u64 = (float_bits<<32) | tag; tag for h(t) = t+1; slot = t&3.
//                  memset(0): h(-1)=0 with tag 0 lives in slot 3 (=(-1)&3). OK.
//  bytes [2MB, 2MB+32KB): flags, one int per block, 128B spacing.
//
// Ring-safety sketch (slot depth 4):
//  - same-layer siblings: a block at round R requires siblings >= R-1 (it polls
//    their tag R-1 data), so sibling spread <= 1; writer slot (R)&3 vs reader
//    slot (R-2)&3 never collide.
//  - L1 reads h0(t'=rd-1) slot (rd-1)&3; L0 at round t overwrites slot t&3
//    holding h0(t-4), read by L1 in round t-3 -> L0 waits for L1 flag >= t-2,
//    which in steady state (L1 lag ~1) is satisfied 2 rounds early (off path).
extern "C" __global__ void __launch_bounds__(512, 2)
rnn_persist(const float* __restrict__ x, const int* __restrict__ lengths,
            const float* __restrict__ gW0, const float* __restrict__ gU0,
            const float* __restrict__ gbi0, const float* __restrict__ gbr0,
            const float* __restrict__ gW1, const float* __restrict__ gU1,
            const float* __restrict__ gbi1, const float* __restrict__ gbr1,
            const float* __restrict__ lW0, const float* __restrict__ lU0,
            const float* __restrict__ lb0,
            const float* __restrict__ lW1, const float* __restrict__ lU1,
            const float* __restrict__ lb1,
            const float* __restrict__ outW, const float* __restrict__ outb,
            float* __restrict__ out, float* __restrict__ ws)
{
    const int tid  = threadIdx.x;
    const int lane = tid & 63;
    const int wave = tid >> 6;

    const int slice = blockIdx.x & 15;
    const int rg    = blockIdx.x >> 4;
    const int chain = slice >> 3;
    const int layer = (slice >> 2) & 1;
    const int jt    = slice & 3;
    const int rowbase = rg * 4;
    const int cpos  = jt * 64 + lane;

    unsigned long long* H = (unsigned long long*)ws;
    unsigned long long* own   = H + (size_t)(chain * 2 + layer) * 4 * BH;
    unsigned long long* lower = H + (size_t)(chain * 2 + 0) * 4 * BH;
    int* flags  = (int*)((char*)ws + (2 << 20));
    int* myflag = flags + (((chain * 2 + layer) * 16 + rg) * 4 + jt) * 32;

    const int Ka = layer ? Hh : Dd;
    const int KA = Ka + Hh;                   // 352 or 512
    const int ld = chain ? 4 * Hh : 3 * Hh;

    const float* Wm; const float* Um;
    if (chain == 0) { Wm = layer ? gW1 : gW0; Um = layer ? gU1 : gU0; }
    else            { Wm = layer ? lW1 : lW0; Um = layer ? lU1 : lU0; }
    const float* Wp = Wm + cpos;
    const float* Up = Um + cpos - (long)Ka * ld;

    __shared__ __align__(16) float sA[512 * 4];   // A^T[k][4 rows]
    __shared__ float sG[4 * 256];

    const int r = tid >> 6, cc = tid & 63, col = jt * 64 + cc;
    int grow = 0, mylen = 0;
    float b0 = 0, b1 = 0, b2 = 0, b3 = 0, ow = 0, creg = 0.0f;
    if (tid < 256) {
        grow = rowbase + r;
        mylen = lengths[grow];
        if (chain == 0) {
            const float* bi = layer ? gbi1 : gbi0;
            const float* br = layer ? gbr1 : gbr0;
            b0 = bi[col] + br[col];
            b1 = bi[Hh + col] + br[Hh + col];
            b2 = bi[2 * Hh + col];
            b3 = br[2 * Hh + col];
        } else {
            const float* bb = layer ? lb1 : lb0;
            b0 = bb[col]; b1 = bb[Hh + col]; b2 = bb[2 * Hh + col]; b3 = bb[3 * Hh + col];
        }
        if (layer == 1) ow = outW[chain * Hh + col];
    }
    const float outb0 = outb[0];
    const int kpw = KA >> 3;

    for (int rd = 0; rd <= Tt; ++rd) {
        const bool active = (layer == 0) ? (rd < Tt) : (rd >= 1);
        const int t = (layer == 0) ? rd : rd - 1;

        if (active) {
            // ---- stage A^T: tagged poll is the sync ----
            if (layer == 0) {
                if (tid < 4 * Dd) {
                    const int rr2 = tid & 3, k = tid >> 2;
                    sA[k * 4 + rr2] = x[((long)(rowbase + rr2) * Tt + t) * Dd + k];
                }
                stage2(own + (size_t)((t - 1) & 3) * BH, rowbase, (unsigned)t,
                       sA, Dd, tid);
            } else {
                stage4(lower + (size_t)(t & 3) * BH, (unsigned)(t + 1),
                       own + (size_t)((t - 1) & 3) * BH, (unsigned)t,
                       rowbase, sA, tid);
            }
            for (int i = tid; i < 4 * 256; i += 512) sG[i] = 0.0f;
            __syncthreads();

            // ---- GEMM ----
            {
                const int k0 = wave * kpw, k1 = k0 + kpw;
                if (chain == 0) {
                    float4 acc[3];
                    int a = k0, b = (k1 < Ka) ? k1 : Ka;
                    if (a < b) {
                        acc[0] = acc[1] = acc[2] = float4{0, 0, 0, 0};
                        gemm_range<3>(Wp, ld, sA, a, b, acc);
                        addslot(sG, 0, lane, acc[0]);
                        addslot(sG, 1, lane, acc[1]);
                        addslot(sG, 2, lane, acc[2]);
                    }
                    a = (k0 > Ka) ? k0 : Ka; b = k1;
                    if (a < b) {
                        acc[0] = acc[1] = acc[2] = float4{0, 0, 0, 0};
                        gemm_range<3>(Up, ld, sA, a, b, acc);
                        addslot(sG, 0, lane, acc[0]);
                        addslot(sG, 1, lane, acc[1]);
                        addslot(sG, 3, lane, acc[2]);
                    }
                } else {
                    float4 acc[4];
                    int a = k0, b = (k1 < Ka) ? k1 : Ka;
                    if (a < b) {
                        acc[0] = acc[1] = acc[2] = acc[3] = float4{0, 0, 0, 0};
                        gemm_range<4>(Wp, ld, sA, a, b, acc);
                        addslot(sG, 0, lane, acc[0]); addslot(sG, 1, lane, acc[1]);
                        addslot(sG, 2, lane, acc[2]); addslot(sG, 3, lane, acc[3]);
                    }
                    a = (k0 > Ka) ? k0 : Ka; b = k1;
                    if (a < b) {
                        acc[0] = acc[1] = acc[2] = acc[3] = float4{0, 0, 0, 0};
                        gemm_range<4>(Up, ld, sA, a, b, acc);
                        addslot(sG, 0, lane, acc[0]); addslot(sG, 1, lane, acc[1]);
                        addslot(sG, 2, lane, acc[2]); addslot(sG, 3, lane, acc[3]);
                    }
                }
            }
            __syncthreads();

            // ---- L0 anti-clobber: before overwriting slot t&3 (holds h0(t-4)),
            //      ensure L1 finished round t-3 (flag >= t-2). 2 rounds of slack.
            if (layer == 0 && t >= 3) {
                if (wave == 0) {
                    const int* fp = flags + (((chain * 2 + 1) * 16 + rg) * 4 + (lane & 3)) * 32;
                    bool ok = (lane >= 4);
                    for (;;) {
                        if (!ok) ok = (__hip_atomic_load(fp, __ATOMIC_ACQUIRE,
                                                         __HIP_MEMORY_SCOPE_AGENT) >= t - 2);
                        if ((__ballot(ok) & 0xFull) == 0xFull) break;
                        __builtin_amdgcn_s_sleep(1);
                    }
                }
                __syncthreads();
            }

            // ---- state update + RMW publish (visible at coherence point) ----
            if (tid < 256) {
                const float s0 = sG[tid], s1 = sG[256 + tid];
                const float s2 = sG[512 + tid], s3 = sG[768 + tid];
                const float hold = sA[(Ka + col) * 4 + r];
                const bool frozen = (t >= mylen);
                float hn;
                if (chain == 0) {
                    const float z   = sigf(s0 + b0);
                    const float rr2 = sigf(s1 + b1);
                    const float hh  = tanhf(s2 + b2 + rr2 * (s3 + b3));
                    hn = z * hold + (1.0f - z) * hh;
                    if (frozen) hn = hold;
                } else {
                    const float i_ = sigf(s0 + b0);
                    const float f_ = sigf(s1 + b1);
                    float cn = f_ * creg + i_ * tanhf(s2 + b2);
                    hn = sigf(s3 + b3) * tanhf(cn);
                    if (frozen) { hn = hold; cn = creg; }
                    creg = cn;
                }
                atomicExch(&own[(size_t)(t & 3) * BH + grow * Hh + col],
                           ((unsigned long long)__float_as_uint(hn) << 32)
                           | (unsigned)(t + 1));
                if (layer == 1) {
                    float v = hn * ow;
                    for (int o = 32; o > 0; o >>= 1) v += __shfl_down(v, o);
                    if (cc == 0)
                        atomicAdd(&out[(long)grow * Tt + t],
                                  v + ((chain == 1 && jt == 0) ? outb0 : 0.0f));
                }
            }
        }

        // ---- progress flag via RMW (drained by the syncthreads above) ----
        __syncthreads();
        if (tid == 0) atomicExch(myflag, rd + 1);
    }
}

extern "C" void kernel_launch(void* const* d_in, const int* in_sizes, int n_in,
                              void* d_out, int out_size, void* d_ws, size_t ws_size,
                              hipStream_t stream) {
    const float* x       = (const float*)d_in[0];
    const int*   lengths = (const int*)d_in[1];
    const float* gW0  = (const float*)d_in[2];
    const float* gU0  = (const float*)d_in[3];
    const float* gbi0 = (const float*)d_in[4];
    const float* gbr0 = (const float*)d_in[5];
    const float* gW1  = (const float*)d_in[6];
    const float* gU1  = (const float*)d_in[7];
    const float* gbi1 = (const float*)d_in[8];
    const float* gbr1 = (const float*)d_in[9];
    const float* lW0  = (const float*)d_in[10];
    const float* lU0  = (const float*)d_in[11];
    const float* lb0  = (const float*)d_in[12];
    const float* lW1  = (const float*)d_in[13];
    const float* lU1  = (const float*)d_in[14];
    const float* lb1  = (const float*)d_in[15];
    const float* outW = (const float*)d_in[16];
    const float* outb = (const float*)d_in[17];
    float* out = (float*)d_out;
    float* ws  = (float*)d_ws;

    // zero 4-slot tagged h rings (2MB) + flags (32KB)
    hipMemsetAsync(d_ws, 0, (2 << 20) + 32 * 1024, stream);
    hipMemsetAsync(d_out, 0, (size_t)out_size * sizeof(float), stream);

    rnn_persist<<<dim3(256), dim3(512), 0, stream>>>(
        x, lengths, gW0, gU0, gbi0, gbr0, gW1, gU1, gbi1, gbr1,
        lW0, lU0, lb0, lW1, lU1, lb1, outW, outb, out, ws);
}